// Round 15
// baseline (427.515 us; speedup 1.0000x reference)
//
#include <hip/hip_runtime.h>
#include <cstdint>
#include <cstddef>

// LSTM cell: B=16384, IN=HID=512.
// R16 = LDS-FREE fragment-streaming GEMM. R15's skel bisection: sync
// skeleton 862 cy/phase (MFMA floor 620 + 242 sync), memory +788 cy/phase
// == LDS-port arithmetic (48 reads + 16 gload-writes)*12cy ~= 740: the
// single per-CU LDS port is co-saturated with the MFMA pipes (0.93 ratio)
// -> NO schedule can fix it; the LDS data path itself must go.
// Fix: pack_a/pack_w write FRAGMENT-MAJOR layouts (each 1KB MFMA fragment
// contiguous in lane order), so fragment loads are single coalesced
// global_load_dwordx4 (saddr=phase base, voff=frag-const + lane*16).
// No LDS, no staging, no barriers. 4 waves/block (2x2), wave tile 128x128
// (acc 8x8 f32x4 = 256 VGPR), 32 phases: {vmcnt(16) -> 64 MFMA -> issue
// phase p+2's 16 loads into the just-freed set}. Ledger: 32 outstanding at
// loop top, wait 16 drains phase p; lead = 64 MFMA = 1242 cy >> L2/L3 lat.
// A shared by 2 waves (L1-hit), L2 demand 26-52 B/cy/CU < ~56 budget.
// K-accumulation order unchanged (fk ascending) -> absmax identical.

#define BATCH 16384
#define KDIM  1024
#define NPK   2048
#define HIDN  512

#define BM 256
#define BN 256
#define NPH 32            // K phases of 32 (fk)

typedef __bf16 bf16x8 __attribute__((ext_vector_type(8)));
typedef float  f32x4  __attribute__((ext_vector_type(4)));

__device__ __forceinline__ unsigned short f2bf(float f) {
  unsigned int u = __builtin_bit_cast(unsigned int, f);
  u += 0x7fffu + ((u >> 16) & 1u);   // RNE
  return (unsigned short)(u >> 16);
}

__device__ __forceinline__ float fast_sigmoid(float x) {
  return __builtin_amdgcn_rcpf(1.0f + __expf(-x));
}
__device__ __forceinline__ float fast_tanh(float x) {
  return 1.0f - 2.0f * __builtin_amdgcn_rcpf(1.0f + __expf(2.0f * x));
}

// ---------------- prep kernels: FRAGMENT-MAJOR packing ----------------
// Fragment = 16 rows x 32 k of bf16 = 1 KB, laid out lane-major:
//   lane l = ks*16 + rr (ks = k-slot 0..3, rr = row 0..15), 8 elems/lane.
// frag_id = fr*32 + fk  (fr = row/16, fk = k/32). Byte addr of element
// (row,k): frag_id*1024 + (((k>>3)&3)*16 + (row&15))*16 + (k&7)*2.
// Thread handles 4 rows x one 8-k chunk -> 64 B contiguous output.

__global__ __launch_bounds__(256) void pack_a(const float* __restrict__ x,
                                              const float* __restrict__ h,
                                              unsigned short* __restrict__ A) {
  int c = blockIdx.x * 256 + threadIdx.x;   // 524288 threads
  int rr4 = c & 3;
  int ks  = (c >> 2) & 3;
  int fk  = (c >> 4) & 31;
  int fr  = c >> 9;                         // 0..1023
  int k0  = fk * 32 + ks * 8;
  const float* base = (k0 < 512) ? x : h;
  int kk = (k0 < 512) ? k0 : k0 - 512;
  unsigned short* out = A + ((size_t)fr * 32 + fk) * 512 + (ks * 16 + rr4 * 4) * 8;
#pragma unroll
  for (int i = 0; i < 4; ++i) {
    int row = fr * 16 + rr4 * 4 + i;
    const float* src = base + (size_t)row * 512 + kk;
    float4 lo = ((const float4*)src)[0];
    float4 hi = ((const float4*)src)[1];
    union { unsigned short s[8]; uint4 u; } o;
    o.s[0]=f2bf(lo.x); o.s[1]=f2bf(lo.y); o.s[2]=f2bf(lo.z); o.s[3]=f2bf(lo.w);
    o.s[4]=f2bf(hi.x); o.s[5]=f2bf(hi.y); o.s[6]=f2bf(hi.z); o.s[7]=f2bf(hi.w);
    ((uint4*)(out + i * 8))[0] = o.u;
  }
}

struct GatePtrs {
  const float* wx[4];  // gate order: i, g, f, o
  const float* wh[4];
  const float* bx[4];
  const float* bh[4];
};

// Packed-row mapping (UNCHANGED from verified kernels): packed row
// r = b*128 + w64*64 + gate*16 + jl  ->  source j = b*32 + w64*16 + jl.
// New here: fragment-major placement of the packed [2048][1024] matrix.
__global__ __launch_bounds__(256) void pack_w(GatePtrs P,
                                              unsigned short* __restrict__ W,
                                              float* __restrict__ bias) {
  int c = blockIdx.x * 256 + threadIdx.x;   // 65536 threads
  int rr4 = c & 3;
  int ks  = (c >> 2) & 3;
  int fk  = (c >> 4) & 31;
  int fr  = c >> 9;                         // 0..127
  int k0  = fk * 32 + ks * 8;
  int kk = (k0 < 512) ? k0 : k0 - 512;
  unsigned short* out = W + ((size_t)fr * 32 + fk) * 512 + (ks * 16 + rr4 * 4) * 8;
#pragma unroll
  for (int i = 0; i < 4; ++i) {
    int r = fr * 16 + rr4 * 4 + i;
    int b    = r >> 7;
    int rem  = r & 127;
    int w64  = (rem >> 6) & 1;
    int gate = (rem >> 4) & 3;
    int jl   = rem & 15;
    int j = b * 32 + w64 * 16 + jl;
    const float* src = ((k0 < 512) ? P.wx[gate] : P.wh[gate]) + (size_t)j * 512 + kk;
    float4 lo = ((const float4*)src)[0];
    float4 hi = ((const float4*)src)[1];
    union { unsigned short s[8]; uint4 u; } o;
    o.s[0]=f2bf(lo.x); o.s[1]=f2bf(lo.y); o.s[2]=f2bf(lo.z); o.s[3]=f2bf(lo.w);
    o.s[4]=f2bf(hi.x); o.s[5]=f2bf(hi.y); o.s[6]=f2bf(hi.z); o.s[7]=f2bf(hi.w);
    ((uint4*)(out + i * 8))[0] = o.u;
    if (fk == 0 && ks == 0) bias[r] = P.bx[gate][j] + P.bh[gate][j];
  }
}

// ---------------- fused GEMM + LSTM epilogue (LDS-free) ----------------

// asm global load: saddr (SGPR pair, wave-uniform phase base) + 32b voff.
// Opaque to the compiler's waitcnt pass -> manual counted vmcnt only.
#define GLOAD(dst, voff, sptr)                                               \
  asm volatile("global_load_dwordx4 %0, %1, %2"                              \
               : "=v"(dst) : "v"(voff), "s"(sptr))

#define ISSUE_PHASE(aset, bset, pA, pB) do {                                 \
    GLOAD(aset[0], voffA[0], pA); GLOAD(aset[1], voffA[1], pA);              \
    GLOAD(aset[2], voffA[2], pA); GLOAD(aset[3], voffA[3], pA);              \
    GLOAD(aset[4], voffA[4], pA); GLOAD(aset[5], voffA[5], pA);              \
    GLOAD(aset[6], voffA[6], pA); GLOAD(aset[7], voffA[7], pA);              \
    GLOAD(bset[0], voffB[0], pB); GLOAD(bset[1], voffB[1], pB);              \
    GLOAD(bset[2], voffB[2], pB); GLOAD(bset[3], voffB[3], pB);              \
    GLOAD(bset[4], voffB[4], pB); GLOAD(bset[5], voffB[5], pB);              \
    GLOAD(bset[6], voffB[6], pB); GLOAD(bset[7], voffB[7], pB);              \
  } while (0)

#define MFMA64(aset, bset) do {                                              \
    _Pragma("unroll")                                                        \
    for (int mi = 0; mi < 8; ++mi)                                           \
      _Pragma("unroll")                                                      \
      for (int ni = 0; ni < 8; ++ni)                                         \
        acc[mi][ni] = __builtin_amdgcn_mfma_f32_16x16x32_bf16(               \
            aset[mi], bset[ni], acc[mi][ni], 0, 0, 0);                       \
  } while (0)

#define SCB() __builtin_amdgcn_sched_barrier(0)

__global__ __launch_bounds__(256, 1) void lstm_gemm(
    const unsigned short* __restrict__ A,    // frag-major [1024*32] x 1KB
    const unsigned short* __restrict__ W,    // frag-major [128*32] x 1KB
    const float* __restrict__ bias,          // [2048] packed
    const float* __restrict__ Cin,           // [16384,512]
    float* __restrict__ Hout,                // [16384,512]
    float* __restrict__ Cout) {              // [16384,512]
  const int tid  = threadIdx.x;
  const int lane = tid & 63;
  const int wv   = tid >> 6;     // 0..3
  const int wm   = wv >> 1;      // 0..1 (wave row; 2 x 128 = 256)
  const int wn   = wv & 1;       // 0..1 (wave col; 2 x 128 = 256)

  // XCD-aware swizzle: 512 blocks, nwg%8==0 -> bijective.
  const int lin = blockIdx.x;
  const int xcd = lin & 7;
  const int idx = lin >> 3;
  const int bn  = idx & 7;               // 0..7
  const int bm  = (idx >> 3) * 8 + xcd;  // 0..63

  // Per-mi/ni fragment byte offsets (thread-constant VGPRs):
  // frag fr = bm*16 + wm*8 + mi  ->  voffA[mi] = (wm*8+mi)*32 frags * 1KB.
  unsigned int voffA[8], voffB[8];
#pragma unroll
  for (int mi = 0; mi < 8; ++mi)
    voffA[mi] = (unsigned int)((wm * 8 + mi) * 32768 + lane * 16);
#pragma unroll
  for (int ni = 0; ni < 8; ++ni)
    voffB[ni] = (unsigned int)((wn * 8 + ni) * 32768 + lane * 16);

  // Phase-p SGPR bases: baseA + p frags (fk == p).
  const unsigned short* baseA = A + (size_t)bm * 512 * 512;  // bm*512 frags
  const unsigned short* baseB = W + (size_t)bn * 512 * 512;  // bn*512 frags

  f32x4 acc[8][8] = {};        // 256 VGPR accumulator
  bf16x8 aX[8], bX[8];         // ping set (even phases)
  bf16x8 aY[8], bY[8];         // pong set (odd phases)

  // prologue: issue phases 0 and 1 -> 32 loads outstanding
  ISSUE_PHASE(aX, bX, baseA, baseB);
  ISSUE_PHASE(aY, bY, baseA + 512, baseB + 512);

#pragma unroll 1
  for (int p = 0; p < NPH; p += 2) {
    const int p2 = (p + 2 < NPH) ? p + 2 : NPH - 2;  // tail: dead re-issue,
    const int p3 = (p + 3 < NPH) ? p + 3 : NPH - 1;  // keeps ledger uniform
    // even phase p: X ready (wait drains p's 16; p+1's 16 remain)
    asm volatile("s_waitcnt vmcnt(16)" ::: "memory");
    SCB();
    MFMA64(aX, bX);
    SCB();
    ISSUE_PHASE(aX, bX, baseA + (size_t)p2 * 512, baseB + (size_t)p2 * 512);
    // odd phase p+1: Y ready
    asm volatile("s_waitcnt vmcnt(16)" ::: "memory");
    SCB();
    MFMA64(aY, bY);
    SCB();
    ISSUE_PHASE(aY, bY, baseA + (size_t)p3 * 512, baseB + (size_t)p3 * 512);
  }
  asm volatile("s_waitcnt vmcnt(0)" ::: "memory");  // drain tail re-issues
  SCB();

  // ---- epilogue ----
  // C/D frag layout (verified): col = lane&15, row = (lane>>4)*4 + r.
  // Wave cols = wn*128 + ni*16 + jl; packed-row decode: bq = bn*2+wn,
  // gate = ni&3, w64 = ni>>2, j = bq*32 + w64*16 + jl.
  const int jl = lane & 15;
  const int rq = (lane >> 4) << 2;
  const int bq = bn * 2 + wn;            // 0..15
  float bv[8];
#pragma unroll
  for (int ni = 0; ni < 8; ++ni)
    bv[ni] = bias[bq * 128 + (ni >> 2) * 64 + (ni & 3) * 16 + jl];

#pragma unroll
  for (int mi = 0; mi < 8; ++mi) {
    const int row0 = bm * 256 + wm * 128 + mi * 16 + rq;
#pragma unroll
    for (int w64 = 0; w64 < 2; ++w64) {
      const int j = bq * 32 + w64 * 16 + jl;
#pragma unroll
      for (int r = 0; r < 4; ++r) {
        int row = row0 + r;
        float iv = fast_sigmoid(acc[mi][w64 * 4 + 0][r] + bv[w64 * 4 + 0]);
        float gv = fast_tanh   (acc[mi][w64 * 4 + 1][r] + bv[w64 * 4 + 1]);
        float fv = fast_sigmoid(acc[mi][w64 * 4 + 2][r] + bv[w64 * 4 + 2]);
        float ov = fast_sigmoid(acc[mi][w64 * 4 + 3][r] + bv[w64 * 4 + 3]);
        float cold = Cin[(size_t)row * HIDN + j];
        float cnew = fv * cold + iv * gv;
        Hout[(size_t)row * HIDN + j] = ov * fast_tanh(cnew);
        Cout[(size_t)row * HIDN + j] = cnew;
      }
    }
  }
}

// ---------------- launch ----------------

extern "C" void kernel_launch(void* const* d_in, const int* in_sizes, int n_in,
                              void* d_out, int out_size, void* d_ws, size_t ws_size,
                              hipStream_t stream) {
  const float* x   = (const float*)d_in[0];
  const float* h   = (const float*)d_in[1];
  const float* c   = (const float*)d_in[2];
  const float* Wxi = (const float*)d_in[3];  const float* bxi = (const float*)d_in[4];
  const float* Wxo = (const float*)d_in[5];  const float* bxo = (const float*)d_in[6];
  const float* Wxf = (const float*)d_in[7];  const float* bxf = (const float*)d_in[8];
  const float* Wxg = (const float*)d_in[9];  const float* bxg = (const float*)d_in[10];
  const float* Whi = (const float*)d_in[11]; const float* bhi = (const float*)d_in[12];
  const float* Who = (const float*)d_in[13]; const float* bho = (const float*)d_in[14];
  const float* Whf = (const float*)d_in[15]; const float* bhf = (const float*)d_in[16];
  const float* Whg = (const float*)d_in[17]; const float* bhg = (const float*)d_in[18];

  char* ws = (char*)d_ws;
  unsigned short* Apack = (unsigned short*)ws;                              // 32 MB
  unsigned short* Wpack = (unsigned short*)(ws + (size_t)BATCH * KDIM * 2); // 4 MB
  float* biasp = (float*)(ws + (size_t)BATCH * KDIM * 2 + (size_t)NPK * KDIM * 2);

  pack_a<<<(BATCH / 16) * 32 * 16 / 256, 256, 0, stream>>>(x, h, Apack);

  GatePtrs P;
  P.wx[0] = Wxi; P.wx[1] = Wxg; P.wx[2] = Wxf; P.wx[3] = Wxo;
  P.wh[0] = Whi; P.wh[1] = Whg; P.wh[2] = Whf; P.wh[3] = Who;
  P.bx[0] = bxi; P.bx[1] = bxg; P.bx[2] = bxf; P.bx[3] = bxo;
  P.bh[0] = bhi; P.bh[1] = bhg; P.bh[2] = bhf; P.bh[3] = bho;
  pack_w<<<(NPK / 16) * 32 * 16 / 256, 256, 0, stream>>>(P, Wpack, biasp);

  float* Hout = (float*)d_out;
  float* Cout = Hout + (size_t)BATCH * HIDN;
  lstm_gemm<<<dim3((BATCH / BM) * (NPK / BN)), 256, 0, stream>>>(
      Apack, Wpack, biasp, c, Hout, Cout);
}